// Round 1
// baseline (19155.342 us; speedup 1.0000x reference)
//
#include <hip/hip_runtime.h>
#include <hip/hip_bf16.h>

#define MQ   65536
#define NS   32
#define EDIM 64
#define FFD  128
#define OUTD 128
#define NL   2

#define ST   65    // padded stride for 64-wide LDS rows (conflict-free)
#define STF  130   // padded stride for 128-wide rows
#define STA  33    // padded stride for attention rows

// dot of 64-elem register array with 64-elem global row (float4, 4 FMA chains)
__device__ __forceinline__ float dot64(const float* s, const float* __restrict__ w) {
  const float4* w4 = (const float4*)w;
  float a0 = 0.f, a1 = 0.f, a2 = 0.f, a3 = 0.f;
#pragma unroll
  for (int i = 0; i < 16; i++) {
    float4 wv = w4[i];
    a0 = fmaf(s[4*i+0], wv.x, a0);
    a1 = fmaf(s[4*i+1], wv.y, a1);
    a2 = fmaf(s[4*i+2], wv.z, a2);
    a3 = fmaf(s[4*i+3], wv.w, a3);
  }
  return (a0 + a1) + (a2 + a3);
}

__device__ __forceinline__ float dot32(const float* s, const float* __restrict__ w) {
  const float4* w4 = (const float4*)w;
  float a0 = 0.f, a1 = 0.f, a2 = 0.f, a3 = 0.f;
#pragma unroll
  for (int i = 0; i < 8; i++) {
    float4 wv = w4[i];
    a0 = fmaf(s[4*i+0], wv.x, a0);
    a1 = fmaf(s[4*i+1], wv.y, a1);
    a2 = fmaf(s[4*i+2], wv.z, a2);
    a3 = fmaf(s[4*i+3], wv.w, a3);
  }
  return (a0 + a1) + (a2 + a3);
}

// layernorm of one 64-wide LDS row (serial per token)
__device__ __forceinline__ void layernorm_row(const float* x, float* dst,
                                              const float* __restrict__ g,
                                              const float* __restrict__ b) {
  float mu = 0.f;
#pragma unroll
  for (int c = 0; c < 64; c++) mu += x[c];
  mu *= (1.f / 64.f);
  float v = 0.f;
#pragma unroll
  for (int c = 0; c < 64; c++) { float d = x[c] - mu; v = fmaf(d, d, v); }
  float inv = rsqrtf(v * (1.f / 64.f) + 1e-5f);
#pragma unroll
  for (int c = 0; c < 64; c++) dst[c] = (x[c] - mu) * inv * g[c] + b[c];
}

extern "C" __global__ __launch_bounds__(128)
void nvt_fused(const float* __restrict__ xyz,
               const float* __restrict__ new_xyz,
               const float* __restrict__ features,
               const int* __restrict__ group_idx,
               const unsigned char* __restrict__ empty_mask,
               const float* __restrict__ pos_w1,
               const float* __restrict__ pos_bn_g,
               const float* __restrict__ pos_bn_b,
               const float* __restrict__ pos_bn_mean,
               const float* __restrict__ pos_bn_var,
               const float* __restrict__ pos_w2,
               const float* __restrict__ pos_b2,
               const float* __restrict__ ln1_g, const float* __restrict__ ln1_b,
               const float* __restrict__ qkv_w, const float* __restrict__ qkv_b,
               const float* __restrict__ aow,  const float* __restrict__ aob,
               const float* __restrict__ ln2_g, const float* __restrict__ ln2_b,
               const float* __restrict__ f1w,  const float* __restrict__ f1b,
               const float* __restrict__ f2w,  const float* __restrict__ f2b,
               const float* __restrict__ out_w, const float* __restrict__ out_b,
               float* __restrict__ out)
{
  __shared__ float sm[11456];
  const int m   = blockIdx.x;
  const int tid = threadIdx.x;
  const int t   = tid & 31;   // token
  const int og  = tid >> 5;   // output group 0..3

  float* xb = sm;             // x      [32][65]
  float* sb = sm + 2080;      // s / a  [32][65]
  float* qb = sm + 4160;      // q      [32][65]
  float* kb = sm + 6240;      // k      [32][65]
  float* vb = sm + 8320;      // v      [32][65]
  float* ab = sm + 10400;     // attn   [32][33] (reused for pooled[64])
  float* fb = sm + 4160;      // ff1 out [32][130] aliases qb+kb (q/k dead by then)

  const int  idx   = group_idx[m * NS + t];
  const bool empty = empty_mask[m] != 0;

  // ---- gather features -> xb ----
  {
    const float* src = features + (long long)idx * EDIM + og * 16;
#pragma unroll
    for (int i = 0; i < 4; i++) {
      float4 v = ((const float4*)src)[i];
      if (empty) { v.x = 0.f; v.y = 0.f; v.z = 0.f; v.w = 0.f; }
      int base = t * ST + og * 16 + i * 4;
      xb[base+0] = v.x; xb[base+1] = v.y; xb[base+2] = v.z; xb[base+3] = v.w;
    }
  }

  // ---- position encoding (each of the 4 og-threads redundantly computes h) ----
  float gx0 = xyz[idx*3+0] - new_xyz[m*3+0];
  float gx1 = xyz[idx*3+1] - new_xyz[m*3+1];
  float gx2 = xyz[idx*3+2] - new_xyz[m*3+2];
  if (empty) { gx0 = 0.f; gx1 = 0.f; gx2 = 0.f; }
  float h[32];
#pragma unroll
  for (int o = 0; o < 32; o++) {
    float hv = fmaf(gx0, pos_w1[o*3+0], fmaf(gx1, pos_w1[o*3+1], gx2 * pos_w1[o*3+2]));
    hv = (hv - pos_bn_mean[o]) * pos_bn_g[o] * rsqrtf(pos_bn_var[o] + 1e-5f) + pos_bn_b[o];
    h[o] = fmaxf(hv, 0.f);
  }
  __syncthreads();
#pragma unroll 2
  for (int i = 0; i < 16; i++) {
    int c = og * 16 + i;
    xb[t * ST + c] += pos_b2[c] + dot32(h, pos_w2 + c * 32);
  }

  // ---- transformer layers ----
  for (int l = 0; l < NL; l++) {
    const float* Wq = qkv_w + l * 192 * 64;
    const float* Bq = qkv_b + l * 192;
    __syncthreads();
    // LN1: xb -> sb
    if (tid < 32) layernorm_row(xb + t * ST, sb + t * ST, ln1_g + l * 64, ln1_b + l * 64);
    __syncthreads();
    // qkv
    {
      float s[64];
#pragma unroll
      for (int k2 = 0; k2 < 64; k2++) s[k2] = sb[t * ST + k2];
#pragma unroll 2
      for (int i = 0; i < 48; i++) {
        int o = og + 4 * i;
        float acc = Bq[o] + dot64(s, Wq + o * 64);
        float* dst = (o < 64)  ? (qb + t * ST + o)
                   : (o < 128) ? (kb + t * ST + (o - 64))
                               : (vb + t * ST + (o - 128));
        *dst = acc;
      }
    }
    __syncthreads();
    // scores: ab[t][j] = 0.125 * q[t].k[j]
    {
      float q[64];
#pragma unroll
      for (int k2 = 0; k2 < 64; k2++) q[k2] = qb[t * ST + k2];
#pragma unroll 2
      for (int i = 0; i < 8; i++) {
        int j = og + 4 * i;
        const float* kr = kb + j * ST;
        float a0 = 0.f, a1 = 0.f, a2 = 0.f, a3 = 0.f;
#pragma unroll
        for (int k2 = 0; k2 < 16; k2++) {
          a0 = fmaf(q[4*k2+0], kr[4*k2+0], a0);
          a1 = fmaf(q[4*k2+1], kr[4*k2+1], a1);
          a2 = fmaf(q[4*k2+2], kr[4*k2+2], a2);
          a3 = fmaf(q[4*k2+3], kr[4*k2+3], a3);
        }
        ab[t * STA + j] = ((a0 + a1) + (a2 + a3)) * 0.125f;
      }
    }
    __syncthreads();
    // softmax rows
    if (tid < 32) {
      float* r = ab + t * STA;
      float mx = -1e30f;
#pragma unroll
      for (int j = 0; j < 32; j++) mx = fmaxf(mx, r[j]);
      float ssum = 0.f;
#pragma unroll
      for (int j = 0; j < 32; j++) { float e = __expf(r[j] - mx); r[j] = e; ssum += e; }
      float inv = 1.f / ssum;
#pragma unroll
      for (int j = 0; j < 32; j++) r[j] *= inv;
    }
    __syncthreads();
    // PV -> sb
    {
      float a[32];
#pragma unroll
      for (int j = 0; j < 32; j++) a[j] = ab[t * STA + j];
#pragma unroll 2
      for (int i = 0; i < 16; i++) {
        int c = og * 16 + i;
        float a0 = 0.f, a1 = 0.f, a2 = 0.f, a3 = 0.f;
#pragma unroll
        for (int j = 0; j < 8; j++) {
          a0 = fmaf(a[4*j+0], vb[(4*j+0)*ST + c], a0);
          a1 = fmaf(a[4*j+1], vb[(4*j+1)*ST + c], a1);
          a2 = fmaf(a[4*j+2], vb[(4*j+2)*ST + c], a2);
          a3 = fmaf(a[4*j+3], vb[(4*j+3)*ST + c], a3);
        }
        sb[t * ST + c] = (a0 + a1) + (a2 + a3);
      }
    }
    __syncthreads();
    // attn_out: xb += a @ W^T + b
    {
      float a[64];
#pragma unroll
      for (int k2 = 0; k2 < 64; k2++) a[k2] = sb[t * ST + k2];
#pragma unroll 2
      for (int i = 0; i < 16; i++) {
        int c = og + 4 * i;
        xb[t * ST + c] += aob[l * 64 + c] + dot64(a, aow + l * 64 * 64 + c * 64);
      }
    }
    __syncthreads();
    // LN2: xb -> sb
    if (tid < 32) layernorm_row(xb + t * ST, sb + t * ST, ln2_g + l * 64, ln2_b + l * 64);
    __syncthreads();
    // ff1 -> fb (relu)
    {
      float s[64];
#pragma unroll
      for (int k2 = 0; k2 < 64; k2++) s[k2] = sb[t * ST + k2];
#pragma unroll 2
      for (int i = 0; i < 32; i++) {
        int o = og + 4 * i;
        float acc = f1b[l * 128 + o] + dot64(s, f1w + l * 128 * 64 + o * 64);
        fb[t * STF + o] = fmaxf(acc, 0.f);
      }
    }
    __syncthreads();
    // ff2: xb += f @ W2^T + b2  (two register halves of f)
    {
      float fr[64];
      float acc[16];
#pragma unroll
      for (int k2 = 0; k2 < 64; k2++) fr[k2] = fb[t * STF + k2];
#pragma unroll
      for (int i = 0; i < 16; i++) {
        int c = og + 4 * i;
        acc[i] = f2b[l * 64 + c] + dot64(fr, f2w + l * 64 * 128 + c * 128);
      }
#pragma unroll
      for (int k2 = 0; k2 < 64; k2++) fr[k2] = fb[t * STF + 64 + k2];
#pragma unroll
      for (int i = 0; i < 16; i++) {
        int c = og + 4 * i;
        acc[i] += dot64(fr, f2w + l * 64 * 128 + c * 128 + 64);
        xb[t * ST + c] += acc[i];
      }
    }
  }
  __syncthreads();

  // ---- max pool over tokens ----
  if (tid < 64) {
    int c = tid;
    float mx = -1e30f;
#pragma unroll
    for (int r = 0; r < 32; r++) mx = fmaxf(mx, xb[r * ST + c]);
    ab[c] = mx;
  }
  __syncthreads();

  // ---- output projection: 128 outputs, one per thread ----
  {
    float p[64];
#pragma unroll
    for (int c = 0; c < 64; c++) p[c] = ab[c];
    int o = tid;
    out[(long long)m * OUTD + o] = out_b[o] + dot64(p, out_w + o * 64);
  }
}

extern "C" void kernel_launch(void* const* d_in, const int* in_sizes, int n_in,
                              void* d_out, int out_size, void* d_ws, size_t ws_size,
                              hipStream_t stream) {
  const float* xyz         = (const float*)d_in[0];
  const float* new_xyz     = (const float*)d_in[1];
  const float* features    = (const float*)d_in[2];
  const int*   group_idx   = (const int*)d_in[3];
  const unsigned char* empty_mask = (const unsigned char*)d_in[4];
  const float* pos_w1      = (const float*)d_in[5];
  const float* pos_bn_g    = (const float*)d_in[6];
  const float* pos_bn_b    = (const float*)d_in[7];
  const float* pos_bn_mean = (const float*)d_in[8];
  const float* pos_bn_var  = (const float*)d_in[9];
  const float* pos_w2      = (const float*)d_in[10];
  const float* pos_b2      = (const float*)d_in[11];
  const float* ln1_g       = (const float*)d_in[12];
  const float* ln1_b       = (const float*)d_in[13];
  const float* qkv_w       = (const float*)d_in[14];
  const float* qkv_b       = (const float*)d_in[15];
  const float* aow         = (const float*)d_in[16];
  const float* aob         = (const float*)d_in[17];
  const float* ln2_g       = (const float*)d_in[18];
  const float* ln2_b       = (const float*)d_in[19];
  const float* f1w         = (const float*)d_in[20];
  const float* f1b         = (const float*)d_in[21];
  const float* f2w         = (const float*)d_in[22];
  const float* f2b         = (const float*)d_in[23];
  const float* out_w       = (const float*)d_in[24];
  const float* out_b       = (const float*)d_in[25];
  float* out = (float*)d_out;

  dim3 grid(MQ);
  dim3 block(128);
  hipLaunchKernelGGL(nvt_fused, grid, block, 0, stream,
                     xyz, new_xyz, features, group_idx, empty_mask,
                     pos_w1, pos_bn_g, pos_bn_b, pos_bn_mean, pos_bn_var,
                     pos_w2, pos_b2, ln1_g, ln1_b, qkv_w, qkv_b, aow, aob,
                     ln2_g, ln2_b, f1w, f1b, f2w, f2b, out_w, out_b, out);
}

// Round 2
// 1563.821 us; speedup vs baseline: 12.2491x; 12.2491x over previous
//
#include <hip/hip_runtime.h>
#include <hip/hip_bf16.h>
#include <math.h>

#define MQ   65536
#define NSOK 32
#define OUTD 128

typedef __attribute__((ext_vector_type(8))) short bf16x8;
typedef __attribute__((ext_vector_type(4))) short bf16x4;
typedef __attribute__((ext_vector_type(4))) float f32x4;

// ws byte offsets (bf16 weights + folded pos params)
#define WS_QKV   0        // 2*192*64 bf16 = 49152B
#define WS_AOW   49152    // 2*64*64       = 16384B
#define WS_F1W   65536    // 2*128*64      = 32768B
#define WS_F2W   98304    // 2*64*128      = 32768B
#define WS_PW2   131072   // 64*32         = 4096B
#define WS_W1F   135168   // 32*3 f32      = 384B
#define WS_PBF   135552   // 32 f32        = 128B

__device__ __forceinline__ unsigned short f2bf(float f) {
  unsigned u = __float_as_uint(f);
  u = (u + 0x7FFFu + ((u >> 16) & 1u)) >> 16;   // RTN
  return (unsigned short)u;
}

__device__ __forceinline__ f32x4 mfma16(bf16x8 a, bf16x8 b, f32x4 c) {
  return __builtin_amdgcn_mfma_f32_16x16x32_bf16(a, b, c, 0, 0, 0);
}

__device__ __forceinline__ bf16x4 pack4(f32x4 a) {
  bf16x4 r;
  r[0] = (short)f2bf(a[0]); r[1] = (short)f2bf(a[1]);
  r[2] = (short)f2bf(a[2]); r[3] = (short)f2bf(a[3]);
  return r;
}

// ---------------- weight conversion prologue ----------------
extern "C" __global__ __launch_bounds__(256)
void convert_weights(const float* __restrict__ qkv_w, const float* __restrict__ aow,
                     const float* __restrict__ f1w,  const float* __restrict__ f2w,
                     const float* __restrict__ pw2,  const float* __restrict__ pw1,
                     const float* __restrict__ png,  const float* __restrict__ pnb,
                     const float* __restrict__ pnm,  const float* __restrict__ pnv,
                     unsigned char* __restrict__ ws) {
  int i = blockIdx.x * 256 + threadIdx.x;
  if (i < 24576) {
    ((unsigned short*)(ws + WS_QKV))[i] = f2bf(qkv_w[i]);
  } else if (i < 32768) {
    int j = i - 24576; ((unsigned short*)(ws + WS_AOW))[j] = f2bf(aow[j]);
  } else if (i < 49152) {
    int j = i - 32768; ((unsigned short*)(ws + WS_F1W))[j] = f2bf(f1w[j]);
  } else if (i < 65536) {
    int j = i - 49152; ((unsigned short*)(ws + WS_F2W))[j] = f2bf(f2w[j]);
  } else if (i < 67584) {
    int j = i - 65536; ((unsigned short*)(ws + WS_PW2))[j] = f2bf(pw2[j]);
  } else if (i < 67616) {
    int k = i - 67584;
    float s = png[k] * rsqrtf(pnv[k] + 1e-5f);
    float* w1f = (float*)(ws + WS_W1F);
    float* pbf = (float*)(ws + WS_PBF);
    w1f[k*3+0] = pw1[k*3+0] * s;
    w1f[k*3+1] = pw1[k*3+1] * s;
    w1f[k*3+2] = pw1[k*3+2] * s;
    pbf[k] = pnb[k] - pnm[k] * s;
  }
}

// ---------------- main fused kernel: 1 group / block, 2 waves ----------------
extern "C" __global__ __launch_bounds__(128, 2)
void nvt_mfma(const float* __restrict__ xyz,
              const float* __restrict__ new_xyz,
              const float* __restrict__ features,
              const int* __restrict__ group_idx,
              const unsigned char* __restrict__ empty_mask,
              const float* __restrict__ pos_b2,
              const float* __restrict__ ln1_g, const float* __restrict__ ln1_b,
              const float* __restrict__ qkv_b,
              const float* __restrict__ aob,
              const float* __restrict__ ln2_g, const float* __restrict__ ln2_b,
              const float* __restrict__ f1b,
              const float* __restrict__ f2b,
              const float* __restrict__ out_w, const float* __restrict__ out_b,
              const unsigned char* __restrict__ ws,
              float* __restrict__ out) {
  // LDS: x f32 [32][68] | S bf16 [32][72] (alias h[32][40], P[32][40], part f32[128])
  //      Q [32][72] | K [32][72] (alias F [32][136], A2=Q) | Vt [64][40]
  __shared__ __align__(16) unsigned char smem[27648];
  float*          xf = (float*)smem;                       // stride 68 f32 (272B, 17 gran)
  unsigned short* S  = (unsigned short*)(smem + 8704);     // stride 72 bf16 (144B, 9 gran)
  unsigned short* Qb = (unsigned short*)(smem + 13312);    // stride 72
  unsigned short* Kb = (unsigned short*)(smem + 17920);    // stride 72
  unsigned short* Fb = (unsigned short*)(smem + 13312);    // stride 136 (272B, 17 gran)
  unsigned short* Vt = (unsigned short*)(smem + 22528);    // [64][40] (80B, 5 gran)
  unsigned short* Hs = S;                                  // h staging [32][40]
  unsigned short* Pb = S;                                  // P [32][40]
  float*          part = (float*)(smem + 8704);            // [2][64]
  unsigned short* A2 = Qb;                                 // attn result staging

  const unsigned short* qkvw_b = (const unsigned short*)(ws + WS_QKV);
  const unsigned short* aow_b  = (const unsigned short*)(ws + WS_AOW);
  const unsigned short* f1w_b  = (const unsigned short*)(ws + WS_F1W);
  const unsigned short* f2w_b  = (const unsigned short*)(ws + WS_F2W);
  const unsigned short* w2b    = (const unsigned short*)(ws + WS_PW2);
  const float* w1f = (const float*)(ws + WS_W1F);
  const float* pbf = (const float*)(ws + WS_PBF);

  const int m    = blockIdx.x;
  const int tid  = threadIdx.x;
  const int w    = tid >> 6;       // wave 0/1
  const int lane = tid & 63;
  const int lr   = lane & 15;      // frag row/col
  const int hi   = lane >> 4;      // 0..3
  const bool empty = empty_mask[m] != 0;

  // ---- stage A: gather features -> x ; compute h -> Hs ----
  {
    int t = tid >> 2, q = tid & 3;
    int idx = group_idx[m * 32 + t];
    const float4* src = (const float4*)(features + (size_t)idx * 64 + q * 16);
#pragma unroll
    for (int i = 0; i < 4; i++) {
      float4 v = src[i];
      if (empty) { v.x = 0.f; v.y = 0.f; v.z = 0.f; v.w = 0.f; }
      *(float4*)&xf[t * 68 + q * 16 + i * 4] = v;
    }
  }
  {
    int t = tid & 31, kb = tid >> 5;   // kb: 8-k block
    int idx = group_idx[m * 32 + t];
    float g0 = xyz[idx*3+0] - new_xyz[m*3+0];
    float g1 = xyz[idx*3+1] - new_xyz[m*3+1];
    float g2 = xyz[idx*3+2] - new_xyz[m*3+2];
    if (empty) { g0 = 0.f; g1 = 0.f; g2 = 0.f; }
    bf16x8 hv;
#pragma unroll
    for (int j = 0; j < 8; j++) {
      int k = kb * 8 + j;
      float hp = fmaf(g0, w1f[k*3+0], fmaf(g1, w1f[k*3+1], g2 * w1f[k*3+2])) + pbf[k];
      hv[j] = (short)f2bf(fmaxf(hp, 0.f));
    }
    *(bf16x8*)&Hs[t * 40 + kb * 8] = hv;
  }
  __syncthreads();

  // ---- pos MLP second layer via MFMA: x += h @ w2^T + b2 ----
  {
    bf16x8 bh[2];
#pragma unroll
    for (int nt = 0; nt < 2; nt++)
      bh[nt] = *(const bf16x8*)&Hs[(nt * 16 + lr) * 40 + hi * 8];
#pragma unroll
    for (int mi = 0; mi < 2; mi++) {
      int mt = w + mi * 2;
      bf16x8 a = *(const bf16x8*)(w2b + (mt * 16 + lr) * 32 + hi * 8);
      float4 b4 = *(const float4*)(pos_b2 + mt * 16 + hi * 4);
      f32x4 bias; bias[0] = b4.x; bias[1] = b4.y; bias[2] = b4.z; bias[3] = b4.w;
#pragma unroll
      for (int nt = 0; nt < 2; nt++) {
        f32x4 acc = mfma16(a, bh[nt], bias);
        float4* px = (float4*)&xf[(nt * 16 + lr) * 68 + mt * 16 + hi * 4];
        float4 v = *px;
        v.x += acc[0]; v.y += acc[1]; v.z += acc[2]; v.w += acc[3];
        *px = v;
      }
    }
  }

  // ---- transformer layers ----
  for (int ly = 0; ly < 2; ly++) {
    // LN1: x -> S (bf16)
    __syncthreads();
    {
      int t = tid >> 2, q = tid & 3;
      float vals[16];
      float s = 0.f, s2 = 0.f;
#pragma unroll
      for (int i = 0; i < 4; i++) {
        float4 v = *(const float4*)&xf[t * 68 + q * 16 + i * 4];
        vals[i*4+0] = v.x; vals[i*4+1] = v.y; vals[i*4+2] = v.z; vals[i*4+3] = v.w;
        s += v.x + v.y + v.z + v.w;
        s2 += v.x*v.x + v.y*v.y + v.z*v.z + v.w*v.w;
      }
      s  += __shfl_xor(s, 1);  s  += __shfl_xor(s, 2);
      s2 += __shfl_xor(s2, 1); s2 += __shfl_xor(s2, 2);
      float mu = s * (1.f/64.f);
      float var = s2 * (1.f/64.f) - mu * mu;
      float inv = rsqrtf(fmaxf(var, 0.f) + 1e-5f);
      bf16x8 o0, o1;
#pragma unroll
      for (int i = 0; i < 16; i++) {
        int c = q * 16 + i;
        float gg = ln1_g[ly*64 + c], bb = ln1_b[ly*64 + c];
        unsigned short r = f2bf((vals[i] - mu) * inv * gg + bb);
        if (i < 8) o0[i] = (short)r; else o1[i-8] = (short)r;
      }
      *(bf16x8*)&S[t * 72 + q * 16]     = o0;
      *(bf16x8*)&S[t * 72 + q * 16 + 8] = o1;
    }
    __syncthreads();

    // qkv: D[o][t] = Wqkv rows x S rows ; store Q,K row-major [t][o], V -> Vt[c][t]
    {
      bf16x8 bs[2][2];
#pragma unroll
      for (int nt = 0; nt < 2; nt++)
#pragma unroll
        for (int kt = 0; kt < 2; kt++)
          bs[nt][kt] = *(const bf16x8*)&S[(nt * 16 + lr) * 72 + kt * 32 + hi * 8];
      const unsigned short* Wq = qkvw_b + ly * 192 * 64;
      const float* Bq = qkv_b + ly * 192;
      for (int mt = w; mt < 12; mt += 2) {
        bf16x8 a[2];
#pragma unroll
        for (int kt = 0; kt < 2; kt++)
          a[kt] = *(const bf16x8*)(Wq + (mt * 16 + lr) * 64 + kt * 32 + hi * 8);
        float4 b4 = *(const float4*)(Bq + mt * 16 + hi * 4);
#pragma unroll
        for (int nt = 0; nt < 2; nt++) {
          f32x4 acc; acc[0] = b4.x; acc[1] = b4.y; acc[2] = b4.z; acc[3] = b4.w;
#pragma unroll
          for (int kt = 0; kt < 2; kt++) acc = mfma16(a[kt], bs[nt][kt], acc);
          int t = nt * 16 + lr;
          if (mt < 8) {
            unsigned short* dst = (mt < 4) ? Qb : Kb;
            *(bf16x4*)&dst[t * 72 + (mt & 3) * 16 + hi * 4] = pack4(acc);
          } else {
            int c0 = (mt - 8) * 16 + hi * 4;
#pragma unroll
            for (int r = 0; r < 4; r++) Vt[(c0 + r) * 40 + t] = f2bf(acc[r]);
          }
        }
      }
    }
    __syncthreads();

    // scores D[j][i] = K rows x Q rows (wave w owns i-tile w); softmax in-register
    {
      bf16x8 ak[2][2], bq[2];
#pragma unroll
      for (int jt = 0; jt < 2; jt++)
#pragma unroll
        for (int kt = 0; kt < 2; kt++)
          ak[jt][kt] = *(const bf16x8*)&Kb[(jt * 16 + lr) * 72 + kt * 32 + hi * 8];
#pragma unroll
      for (int kt = 0; kt < 2; kt++)
        bq[kt] = *(const bf16x8*)&Qb[(w * 16 + lr) * 72 + kt * 32 + hi * 8];
      f32x4 p[2];
#pragma unroll
      for (int jt = 0; jt < 2; jt++) {
        f32x4 acc; acc[0] = 0.f; acc[1] = 0.f; acc[2] = 0.f; acc[3] = 0.f;
#pragma unroll
        for (int kt = 0; kt < 2; kt++) acc = mfma16(ak[jt][kt], bq[kt], acc);
        p[jt] = acc;
      }
      float mx = -3.4e38f;
#pragma unroll
      for (int jt = 0; jt < 2; jt++)
#pragma unroll
        for (int r = 0; r < 4; r++) { p[jt][r] *= 0.125f; mx = fmaxf(mx, p[jt][r]); }
      mx = fmaxf(mx, __shfl_xor(mx, 16));
      mx = fmaxf(mx, __shfl_xor(mx, 32));
      float sum = 0.f;
#pragma unroll
      for (int jt = 0; jt < 2; jt++)
#pragma unroll
        for (int r = 0; r < 4; r++) { float e = __expf(p[jt][r] - mx); p[jt][r] = e; sum += e; }
      sum += __shfl_xor(sum, 16);
      sum += __shfl_xor(sum, 32);
      float inv = 1.f / sum;
      int irow = w * 16 + lr;
#pragma unroll
      for (int jt = 0; jt < 2; jt++) {
        f32x4 pv; pv[0] = p[jt][0]*inv; pv[1] = p[jt][1]*inv; pv[2] = p[jt][2]*inv; pv[3] = p[jt][3]*inv;
        *(bf16x4*)&Pb[irow * 40 + jt * 16 + hi * 4] = pack4(pv);
      }
    }
    __syncthreads();

    // PV: D[c][t] = Vt rows x P rows -> A2[t][c]
    {
      bf16x8 bp[2];
#pragma unroll
      for (int nt = 0; nt < 2; nt++)
        bp[nt] = *(const bf16x8*)&Pb[(nt * 16 + lr) * 40 + hi * 8];
#pragma unroll
      for (int mi = 0; mi < 2; mi++) {
        int mt = w + mi * 2;
        bf16x8 a = *(const bf16x8*)&Vt[(mt * 16 + lr) * 40 + hi * 8];
#pragma unroll
        for (int nt = 0; nt < 2; nt++) {
          f32x4 acc; acc[0] = 0.f; acc[1] = 0.f; acc[2] = 0.f; acc[3] = 0.f;
          acc = mfma16(a, bp[nt], acc);
          *(bf16x4*)&A2[(nt * 16 + lr) * 72 + mt * 16 + hi * 4] = pack4(acc);
        }
      }
    }
    __syncthreads();

    // attn_out: x += A2 @ Wao^T + b
    {
      bf16x8 ba[2][2];
#pragma unroll
      for (int nt = 0; nt < 2; nt++)
#pragma unroll
        for (int kt = 0; kt < 2; kt++)
          ba[nt][kt] = *(const bf16x8*)&A2[(nt * 16 + lr) * 72 + kt * 32 + hi * 8];
      const unsigned short* Wo = aow_b + ly * 64 * 64;
      const float* Bo = aob + ly * 64;
#pragma unroll
      for (int mi = 0; mi < 2; mi++) {
        int mt = w + mi * 2;
        bf16x8 a[2];
#pragma unroll
        for (int kt = 0; kt < 2; kt++)
          a[kt] = *(const bf16x8*)(Wo + (mt * 16 + lr) * 64 + kt * 32 + hi * 8);
        float4 b4 = *(const float4*)(Bo + mt * 16 + hi * 4);
#pragma unroll
        for (int nt = 0; nt < 2; nt++) {
          f32x4 acc; acc[0] = b4.x; acc[1] = b4.y; acc[2] = b4.z; acc[3] = b4.w;
#pragma unroll
          for (int kt = 0; kt < 2; kt++) acc = mfma16(a[kt], ba[nt][kt], acc);
          float4* px = (float4*)&xf[(nt * 16 + lr) * 68 + mt * 16 + hi * 4];
          float4 v = *px;
          v.x += acc[0]; v.y += acc[1]; v.z += acc[2]; v.w += acc[3];
          *px = v;
        }
      }
    }
    __syncthreads();

    // LN2: x -> S
    {
      int t = tid >> 2, q = tid & 3;
      float vals[16];
      float s = 0.f, s2 = 0.f;
#pragma unroll
      for (int i = 0; i < 4; i++) {
        float4 v = *(const float4*)&xf[t * 68 + q * 16 + i * 4];
        vals[i*4+0] = v.x; vals[i*4+1] = v.y; vals[i*4+2] = v.z; vals[i*4+3] = v.w;
        s += v.x + v.y + v.z + v.w;
        s2 += v.x*v.x + v.y*v.y + v.z*v.z + v.w*v.w;
      }
      s  += __shfl_xor(s, 1);  s  += __shfl_xor(s, 2);
      s2 += __shfl_xor(s2, 1); s2 += __shfl_xor(s2, 2);
      float mu = s * (1.f/64.f);
      float var = s2 * (1.f/64.f) - mu * mu;
      float inv = rsqrtf(fmaxf(var, 0.f) + 1e-5f);
      bf16x8 o0, o1;
#pragma unroll
      for (int i = 0; i < 16; i++) {
        int c = q * 16 + i;
        float gg = ln2_g[ly*64 + c], bb = ln2_b[ly*64 + c];
        unsigned short r = f2bf((vals[i] - mu) * inv * gg + bb);
        if (i < 8) o0[i] = (short)r; else o1[i-8] = (short)r;
      }
      *(bf16x8*)&S[t * 72 + q * 16]     = o0;
      *(bf16x8*)&S[t * 72 + q * 16 + 8] = o1;
    }
    __syncthreads();

    // ff1: F[t][o] = relu(S @ W1^T + b1), o<128
    {
      bf16x8 bs[2][2];
#pragma unroll
      for (int nt = 0; nt < 2; nt++)
#pragma unroll
        for (int kt = 0; kt < 2; kt++)
          bs[nt][kt] = *(const bf16x8*)&S[(nt * 16 + lr) * 72 + kt * 32 + hi * 8];
      const unsigned short* W1 = f1w_b + ly * 128 * 64;
      const float* B1 = f1b + ly * 128;
#pragma unroll
      for (int mi = 0; mi < 4; mi++) {
        int mt = w + mi * 2;
        bf16x8 a[2];
#pragma unroll
        for (int kt = 0; kt < 2; kt++)
          a[kt] = *(const bf16x8*)(W1 + (mt * 16 + lr) * 64 + kt * 32 + hi * 8);
        float4 b4 = *(const float4*)(B1 + mt * 16 + hi * 4);
#pragma unroll
        for (int nt = 0; nt < 2; nt++) {
          f32x4 acc; acc[0] = b4.x; acc[1] = b4.y; acc[2] = b4.z; acc[3] = b4.w;
#pragma unroll
          for (int kt = 0; kt < 2; kt++) acc = mfma16(a[kt], bs[nt][kt], acc);
#pragma unroll
          for (int r = 0; r < 4; r++) acc[r] = fmaxf(acc[r], 0.f);
          *(bf16x4*)&Fb[(nt * 16 + lr) * 136 + mt * 16 + hi * 4] = pack4(acc);
        }
      }
    }
    __syncthreads();

    // ff2: x += F @ W2^T + b2  (K=128 -> 4 ktiles)
    {
      bf16x8 bfr[2][4];
#pragma unroll
      for (int nt = 0; nt < 2; nt++)
#pragma unroll
        for (int kt = 0; kt < 4; kt++)
          bfr[nt][kt] = *(const bf16x8*)&Fb[(nt * 16 + lr) * 136 + kt * 32 + hi * 8];
      const unsigned short* W2 = f2w_b + ly * 64 * 128;
      const float* B2 = f2b + ly * 64;
#pragma unroll
      for (int mi = 0; mi < 2; mi++) {
        int mt = w + mi * 2;
        bf16x8 a[4];
#pragma unroll
        for (int kt = 0; kt < 4; kt++)
          a[kt] = *(const bf16x8*)(W2 + (mt * 16 + lr) * 128 + kt * 32 + hi * 8);
        float4 b4 = *(const float4*)(B2 + mt * 16 + hi * 4);
#pragma unroll
        for (int nt = 0; nt < 2; nt++) {
          f32x4 acc; acc[0] = b4.x; acc[1] = b4.y; acc[2] = b4.z; acc[3] = b4.w;
#pragma unroll
          for (int kt = 0; kt < 4; kt++) acc = mfma16(a[kt], bfr[nt][kt], acc);
          float4* px = (float4*)&xf[(nt * 16 + lr) * 68 + mt * 16 + hi * 4];
          float4 v = *px;
          v.x += acc[0]; v.y += acc[1]; v.z += acc[2]; v.w += acc[3];
          *px = v;
        }
      }
    }
  }
  __syncthreads();

  // ---- max pool over tokens (split rows across waves) ----
  {
    int c = tid & 63, rh = tid >> 6;
    float mx = -3.4e38f;
#pragma unroll
    for (int i = 0; i < 16; i++) mx = fmaxf(mx, xf[(rh * 16 + i) * 68 + c]);
    part[rh * 64 + c] = mx;
  }
  __syncthreads();

  // ---- output projection: 128 outputs, one per thread (f32) ----
  {
    int o = tid;
    const float* wr = out_w + o * 64;
    float a0 = 0.f, a1 = 0.f, a2 = 0.f, a3 = 0.f;
#pragma unroll
    for (int i = 0; i < 16; i++) {
      float4 wv = *(const float4*)(wr + i * 4);
      float4 p0 = *(const float4*)&part[i * 4];
      float4 p1 = *(const float4*)&part[64 + i * 4];
      a0 = fmaf(fmaxf(p0.x, p1.x), wv.x, a0);
      a1 = fmaf(fmaxf(p0.y, p1.y), wv.y, a1);
      a2 = fmaf(fmaxf(p0.z, p1.z), wv.z, a2);
      a3 = fmaf(fmaxf(p0.w, p1.w), wv.w, a3);
    }
    out[(size_t)m * OUTD + o] = out_b[o] + (a0 + a1) + (a2 + a3);
  }
}

extern "C" void kernel_launch(void* const* d_in, const int* in_sizes, int n_in,
                              void* d_out, int out_size, void* d_ws, size_t ws_size,
                              hipStream_t stream) {
  const float* xyz         = (const float*)d_in[0];
  const float* new_xyz     = (const float*)d_in[1];
  const float* features    = (const float*)d_in[2];
  const int*   group_idx   = (const int*)d_in[3];
  const unsigned char* empty_mask = (const unsigned char*)d_in[4];
  const float* pos_w1      = (const float*)d_in[5];
  const float* pos_bn_g    = (const float*)d_in[6];
  const float* pos_bn_b    = (const float*)d_in[7];
  const float* pos_bn_mean = (const float*)d_in[8];
  const float* pos_bn_var  = (const float*)d_in[9];
  const float* pos_w2      = (const float*)d_in[10];
  const float* pos_b2      = (const float*)d_in[11];
  const float* ln1_g       = (const float*)d_in[12];
  const float* ln1_b       = (const float*)d_in[13];
  const float* qkv_w       = (const float*)d_in[14];
  const float* qkv_b       = (const float*)d_in[15];
  const float* aow         = (const float*)d_in[16];
  const float* aob         = (const float*)d_in[17];
  const float* ln2_g       = (const float*)d_in[18];
  const float* ln2_b       = (const float*)d_in[19];
  const float* f1w         = (const float*)d_in[20];
  const float* f1b         = (const float*)d_in[21];
  const float* f2w         = (const float*)d_in[22];
  const float* f2b         = (const float*)d_in[23];
  const float* out_w       = (const float*)d_in[24];
  const float* out_b       = (const float*)d_in[25];
  float* out = (float*)d_out;
  unsigned char* ws = (unsigned char*)d_ws;

  hipLaunchKernelGGL(convert_weights, dim3(265), dim3(256), 0, stream,
                     qkv_w, aow, f1w, f2w, pos_w2, pos_w1,
                     pos_bn_g, pos_bn_b, pos_bn_mean, pos_bn_var, ws);

  hipLaunchKernelGGL(nvt_mfma, dim3(MQ), dim3(128), 0, stream,
                     xyz, new_xyz, features, group_idx, empty_mask,
                     pos_b2, ln1_g, ln1_b, qkv_b, aob, ln2_g, ln2_b,
                     f1b, f2b, out_w, out_b, ws, out);
}

// Round 7
// 1542.899 us; speedup vs baseline: 12.4152x; 1.0136x over previous
//
#include <hip/hip_runtime.h>
#include <hip/hip_bf16.h>
#include <math.h>

#define MQ   65536
#define NSOK 32
#define OUTD 128

typedef __attribute__((ext_vector_type(8))) short bf16x8;
typedef __attribute__((ext_vector_type(4))) short bf16x4;
typedef __attribute__((ext_vector_type(4))) float f32x4;

// ws byte offsets (bf16 weights + folded pos params)
#define WS_QKV   0        // 2*192*64 bf16 = 49152B
#define WS_AOW   49152    // 2*64*64       = 16384B
#define WS_F1W   65536    // 2*128*64      = 32768B
#define WS_F2W   98304    // 2*64*128      = 32768B
#define WS_PW2   131072   // 64*32         = 4096B
#define WS_W1F   135168   // 32*3 f32      = 384B
#define WS_PBF   135552   // 32 f32        = 128B

__device__ __forceinline__ unsigned short f2bf(float f) {
  unsigned u = __float_as_uint(f);
  u = (u + 0x7FFFu + ((u >> 16) & 1u)) >> 16;   // RTN
  return (unsigned short)u;
}

__device__ __forceinline__ f32x4 mfma16(bf16x8 a, bf16x8 b, f32x4 c) {
  return __builtin_amdgcn_mfma_f32_16x16x32_bf16(a, b, c, 0, 0, 0);
}

// RNE bf16 packing via HIP intrinsics (compiler can fuse to v_cvt_pk_bf16_f32).
__device__ __forceinline__ bf16x4 pack4(f32x4 v) {
  union { __hip_bfloat162 h[2]; bf16x4 s; } c;
  float2 p0; p0.x = v[0]; p0.y = v[1];
  float2 p1; p1.x = v[2]; p1.y = v[3];
  c.h[0] = __float22bfloat162_rn(p0);
  c.h[1] = __float22bfloat162_rn(p1);
  return c.s;
}

__device__ __forceinline__ bf16x8 pack8(const float* v) {
  union { __hip_bfloat162 h[4]; bf16x8 s; } c;
#pragma unroll
  for (int i = 0; i < 4; i++) {
    float2 p; p.x = v[2*i]; p.y = v[2*i+1];
    c.h[i] = __float22bfloat162_rn(p);
  }
  return c.s;
}

// ---------------- weight conversion prologue (unchanged from round 2) ----------------
extern "C" __global__ __launch_bounds__(256)
void convert_weights(const float* __restrict__ qkv_w, const float* __restrict__ aow,
                     const float* __restrict__ f1w,  const float* __restrict__ f2w,
                     const float* __restrict__ pw2,  const float* __restrict__ pw1,
                     const float* __restrict__ png,  const float* __restrict__ pnb,
                     const float* __restrict__ pnm,  const float* __restrict__ pnv,
                     unsigned char* __restrict__ ws) {
  int i = blockIdx.x * 256 + threadIdx.x;
  if (i < 24576) {
    ((unsigned short*)(ws + WS_QKV))[i] = f2bf(qkv_w[i]);
  } else if (i < 32768) {
    int j = i - 24576; ((unsigned short*)(ws + WS_AOW))[j] = f2bf(aow[j]);
  } else if (i < 49152) {
    int j = i - 32768; ((unsigned short*)(ws + WS_F1W))[j] = f2bf(f1w[j]);
  } else if (i < 65536) {
    int j = i - 49152; ((unsigned short*)(ws + WS_F2W))[j] = f2bf(f2w[j]);
  } else if (i < 67584) {
    int j = i - 65536; ((unsigned short*)(ws + WS_PW2))[j] = f2bf(pw2[j]);
  } else if (i < 67616) {
    int k = i - 67584;
    float s = png[k] * rsqrtf(pnv[k] + 1e-5f);
    float* w1f = (float*)(ws + WS_W1F);
    float* pbf = (float*)(ws + WS_PBF);
    w1f[k*3+0] = pw1[k*3+0] * s;
    w1f[k*3+1] = pw1[k*3+1] * s;
    w1f[k*3+2] = pw1[k*3+2] * s;
    pbf[k] = pnb[k] - pnm[k] * s;
  }
}

// ---------------- main fused kernel: 1 group / block, 2 waves (round-2 skeleton) ----------------
extern "C" __global__ __launch_bounds__(128, 2)
void nvt_mfma(const float* __restrict__ xyz,
              const float* __restrict__ new_xyz,
              const float* __restrict__ features,
              const int* __restrict__ group_idx,
              const unsigned char* __restrict__ empty_mask,
              const float* __restrict__ pos_b2,
              const float* __restrict__ ln1_g, const float* __restrict__ ln1_b,
              const float* __restrict__ qkv_b,
              const float* __restrict__ aob,
              const float* __restrict__ ln2_g, const float* __restrict__ ln2_b,
              const float* __restrict__ f1b,
              const float* __restrict__ f2b,
              const float* __restrict__ out_w, const float* __restrict__ out_b,
              const unsigned char* __restrict__ ws,
              float* __restrict__ out) {
  // LDS: x f32 [32][68] | S bf16 [32][72] (alias h[32][40], P[32][40], part f32[128])
  //      Q [32][72] | K [32][72] (alias F [32][136], A2=Q) | Vt [64][40]
  __shared__ __align__(16) unsigned char smem[27648];
  float*          xf = (float*)smem;                       // stride 68 f32
  unsigned short* S  = (unsigned short*)(smem + 8704);     // stride 72 bf16
  unsigned short* Qb = (unsigned short*)(smem + 13312);    // stride 72
  unsigned short* Kb = (unsigned short*)(smem + 17920);    // stride 72
  unsigned short* Fb = (unsigned short*)(smem + 13312);    // stride 136
  unsigned short* Vt = (unsigned short*)(smem + 22528);    // [64][40]
  unsigned short* Hs = S;                                  // h staging [32][40]
  unsigned short* Pb = S;                                  // P [32][40]
  float*          part = (float*)(smem + 8704);            // [2][64]
  unsigned short* A2 = Qb;                                 // attn result staging

  const unsigned short* qkvw_b = (const unsigned short*)(ws + WS_QKV);
  const unsigned short* aow_b  = (const unsigned short*)(ws + WS_AOW);
  const unsigned short* f1w_b  = (const unsigned short*)(ws + WS_F1W);
  const unsigned short* f2w_b  = (const unsigned short*)(ws + WS_F2W);
  const unsigned short* w2b    = (const unsigned short*)(ws + WS_PW2);
  const float* w1f = (const float*)(ws + WS_W1F);
  const float* pbf = (const float*)(ws + WS_PBF);

  const int m    = blockIdx.x;
  const int tid  = threadIdx.x;
  const int w    = tid >> 6;       // wave 0/1
  const int lane = tid & 63;
  const int lr   = lane & 15;      // frag row/col
  const int hi   = lane >> 4;      // 0..3
  const bool empty = empty_mask[m] != 0;

  // ---- stage A: gather features -> x ; compute h -> Hs ----
  {
    int t = tid >> 2, q = tid & 3;
    int idx = group_idx[m * 32 + t];
    const float4* src = (const float4*)(features + (size_t)idx * 64 + q * 16);
#pragma unroll
    for (int i = 0; i < 4; i++) {
      float4 v = src[i];
      if (empty) { v.x = 0.f; v.y = 0.f; v.z = 0.f; v.w = 0.f; }
      *(float4*)&xf[t * 68 + q * 16 + i * 4] = v;
    }
  }
  {
    int t = tid & 31, kb = tid >> 5;   // kb: 8-k block
    int idx = group_idx[m * 32 + t];
    float g0 = xyz[idx*3+0] - new_xyz[m*3+0];
    float g1 = xyz[idx*3+1] - new_xyz[m*3+1];
    float g2 = xyz[idx*3+2] - new_xyz[m*3+2];
    if (empty) { g0 = 0.f; g1 = 0.f; g2 = 0.f; }
    float hf[8];
#pragma unroll
    for (int j = 0; j < 8; j++) {
      int k = kb * 8 + j;
      float hp = fmaf(g0, w1f[k*3+0], fmaf(g1, w1f[k*3+1], g2 * w1f[k*3+2])) + pbf[k];
      hf[j] = fmaxf(hp, 0.f);
    }
    *(bf16x8*)&Hs[t * 40 + kb * 8] = pack8(hf);
  }
  __syncthreads();

  // ---- pos MLP second layer via MFMA: x += h @ w2^T + b2 ----
  {
    bf16x8 bh[2];
#pragma unroll
    for (int nt = 0; nt < 2; nt++)
      bh[nt] = *(const bf16x8*)&Hs[(nt * 16 + lr) * 40 + hi * 8];
#pragma unroll
    for (int mi = 0; mi < 2; mi++) {
      int mt = w + mi * 2;
      bf16x8 a = *(const bf16x8*)(w2b + (mt * 16 + lr) * 32 + hi * 8);
      float4 b4 = *(const float4*)(pos_b2 + mt * 16 + hi * 4);
      f32x4 bias; bias[0] = b4.x; bias[1] = b4.y; bias[2] = b4.z; bias[3] = b4.w;
#pragma unroll
      for (int nt = 0; nt < 2; nt++) {
        f32x4 acc = mfma16(a, bh[nt], bias);
        float4* px = (float4*)&xf[(nt * 16 + lr) * 68 + mt * 16 + hi * 4];
        float4 v = *px;
        v.x += acc[0]; v.y += acc[1]; v.z += acc[2]; v.w += acc[3];
        *px = v;
      }
    }
  }

  // ---- transformer layers ----
  for (int ly = 0; ly < 2; ly++) {
    // LN1: x -> S (bf16)
    __syncthreads();
    {
      int t = tid >> 2, q = tid & 3;
      float vals[16];
      float s = 0.f, s2 = 0.f;
#pragma unroll
      for (int i = 0; i < 4; i++) {
        float4 v = *(const float4*)&xf[t * 68 + q * 16 + i * 4];
        vals[i*4+0] = v.x; vals[i*4+1] = v.y; vals[i*4+2] = v.z; vals[i*4+3] = v.w;
        s += v.x + v.y + v.z + v.w;
        s2 += v.x*v.x + v.y*v.y + v.z*v.z + v.w*v.w;
      }
      s  += __shfl_xor(s, 1);  s  += __shfl_xor(s, 2);
      s2 += __shfl_xor(s2, 1); s2 += __shfl_xor(s2, 2);
      float mu = s * (1.f/64.f);
      float var = s2 * (1.f/64.f) - mu * mu;
      float inv = rsqrtf(fmaxf(var, 0.f) + 1e-5f);
      float tmp[16];
#pragma unroll
      for (int i = 0; i < 16; i++) {
        int c = q * 16 + i;
        tmp[i] = (vals[i] - mu) * inv * ln1_g[ly*64 + c] + ln1_b[ly*64 + c];
      }
      *(bf16x8*)&S[t * 72 + q * 16]     = pack8(tmp);
      *(bf16x8*)&S[t * 72 + q * 16 + 8] = pack8(tmp + 8);
    }
    __syncthreads();

    // qkv: Q,K as D[o][t] (A=W rows), V swapped as D[t][o] (A=S rows) -> packed Vt store
    {
      bf16x8 bs[2][2];
#pragma unroll
      for (int nt = 0; nt < 2; nt++)
#pragma unroll
        for (int kt = 0; kt < 2; kt++)
          bs[nt][kt] = *(const bf16x8*)&S[(nt * 16 + lr) * 72 + kt * 32 + hi * 8];
      const unsigned short* Wq = qkvw_b + ly * 192 * 64;
      const float* Bq = qkv_b + ly * 192;
      // Q (mt 0..3) and K (mt 4..7), split across waves
      for (int mt = w; mt < 8; mt += 2) {
        bf16x8 a[2];
#pragma unroll
        for (int kt = 0; kt < 2; kt++)
          a[kt] = *(const bf16x8*)(Wq + (mt * 16 + lr) * 64 + kt * 32 + hi * 8);
        float4 b4 = *(const float4*)(Bq + mt * 16 + hi * 4);
#pragma unroll
        for (int nt = 0; nt < 2; nt++) {
          f32x4 acc; acc[0] = b4.x; acc[1] = b4.y; acc[2] = b4.z; acc[3] = b4.w;
#pragma unroll
          for (int kt = 0; kt < 2; kt++) acc = mfma16(a[kt], bs[nt][kt], acc);
          int t = nt * 16 + lr;
          unsigned short* dst = (mt < 4) ? Qb : Kb;
          *(bf16x4*)&dst[t * 72 + (mt & 3) * 16 + hi * 4] = pack4(acc);
        }
      }
      // V swapped: D[tok][ch] = mfma(S_rows, Wv_rows); lane holds 4 consecutive
      // tokens (rows hi*4+r) of channel (mtv*16+lr) -> one packed 8B store.
      for (int mtv = w; mtv < 4; mtv += 2) {
        bf16x8 b0 = *(const bf16x8*)(Wq + (128 + mtv * 16 + lr) * 64 + hi * 8);
        bf16x8 b1 = *(const bf16x8*)(Wq + (128 + mtv * 16 + lr) * 64 + 32 + hi * 8);
        float bv = Bq[128 + mtv * 16 + lr];
#pragma unroll
        for (int nt = 0; nt < 2; nt++) {
          f32x4 acc; acc[0] = bv; acc[1] = bv; acc[2] = bv; acc[3] = bv;
          acc = mfma16(bs[nt][0], b0, acc);
          acc = mfma16(bs[nt][1], b1, acc);
          // acc[r] = V[tok = nt*16 + hi*4 + r][ch = mtv*16 + lr]
          *(bf16x4*)&Vt[(mtv * 16 + lr) * 40 + nt * 16 + hi * 4] = pack4(acc);
        }
      }
    }
    __syncthreads();

    // scores D[j][i] = K rows x Q rows (wave w owns i-tile w); softmax in-register
    {
      bf16x8 ak[2][2], bq[2];
#pragma unroll
      for (int jt = 0; jt < 2; jt++)
#pragma unroll
        for (int kt = 0; kt < 2; kt++)
          ak[jt][kt] = *(const bf16x8*)&Kb[(jt * 16 + lr) * 72 + kt * 32 + hi * 8];
#pragma unroll
      for (int kt = 0; kt < 2; kt++)
        bq[kt] = *(const bf16x8*)&Qb[(w * 16 + lr) * 72 + kt * 32 + hi * 8];
      f32x4 p[2];
#pragma unroll
      for (int jt = 0; jt < 2; jt++) {
        f32x4 acc; acc[0] = 0.f; acc[1] = 0.f; acc[2] = 0.f; acc[3] = 0.f;
#pragma unroll
        for (int kt = 0; kt < 2; kt++) acc = mfma16(ak[jt][kt], bq[kt], acc);
        p[jt] = acc;
      }
      float mx = -3.4e38f;
#pragma unroll
      for (int jt = 0; jt < 2; jt++)
#pragma unroll
        for (int r = 0; r < 4; r++) { p[jt][r] *= 0.125f; mx = fmaxf(mx, p[jt][r]); }
      mx = fmaxf(mx, __shfl_xor(mx, 16));
      mx = fmaxf(mx, __shfl_xor(mx, 32));
      float sum = 0.f;
#pragma unroll
      for (int jt = 0; jt < 2; jt++)
#pragma unroll
        for (int r = 0; r < 4; r++) { float e = __expf(p[jt][r] - mx); p[jt][r] = e; sum += e; }
      sum += __shfl_xor(sum, 16);
      sum += __shfl_xor(sum, 32);
      float inv = 1.f / sum;
      int irow = w * 16 + lr;
#pragma unroll
      for (int jt = 0; jt < 2; jt++) {
        f32x4 pv; pv[0] = p[jt][0]*inv; pv[1] = p[jt][1]*inv; pv[2] = p[jt][2]*inv; pv[3] = p[jt][3]*inv;
        *(bf16x4*)&Pb[irow * 40 + jt * 16 + hi * 4] = pack4(pv);
      }
    }
    __syncthreads();

    // PV: D[c][t] = Vt rows x P rows -> A2[t][c]
    {
      bf16x8 bp[2];
#pragma unroll
      for (int nt = 0; nt < 2; nt++)
        bp[nt] = *(const bf16x8*)&Pb[(nt * 16 + lr) * 40 + hi * 8];
#pragma unroll
      for (int mi = 0; mi < 2; mi++) {
        int mt = w + mi * 2;
        bf16x8 a = *(const bf16x8*)&Vt[(mt * 16 + lr) * 40 + hi * 8];
#pragma unroll
        for (int nt = 0; nt < 2; nt++) {
          f32x4 acc; acc[0] = 0.f; acc[1] = 0.f; acc[2] = 0.f; acc[3] = 0.f;
          acc = mfma16(a, bp[nt], acc);
          *(bf16x4*)&A2[(nt * 16 + lr) * 72 + mt * 16 + hi * 4] = pack4(acc);
        }
      }
    }
    __syncthreads();

    // attn_out: x += A2 @ Wao^T + b
    {
      bf16x8 ba[2][2];
#pragma unroll
      for (int nt = 0; nt < 2; nt++)
#pragma unroll
        for (int kt = 0; kt < 2; kt++)
          ba[nt][kt] = *(const bf16x8*)&A2[(nt * 16 + lr) * 72 + kt * 32 + hi * 8];
      const unsigned short* Wo = aow_b + ly * 64 * 64;
      const float* Bo = aob + ly * 64;
#pragma unroll
      for (int mi = 0; mi < 2; mi++) {
        int mt = w + mi * 2;
        bf16x8 a[2];
#pragma unroll
        for (int kt = 0; kt < 2; kt++)
          a[kt] = *(const bf16x8*)(Wo + (mt * 16 + lr) * 64 + kt * 32 + hi * 8);
        float4 b4 = *(const float4*)(Bo + mt * 16 + hi * 4);
#pragma unroll
        for (int nt = 0; nt < 2; nt++) {
          f32x4 acc; acc[0] = b4.x; acc[1] = b4.y; acc[2] = b4.z; acc[3] = b4.w;
#pragma unroll
          for (int kt = 0; kt < 2; kt++) acc = mfma16(a[kt], ba[nt][kt], acc);
          float4* px = (float4*)&xf[(nt * 16 + lr) * 68 + mt * 16 + hi * 4];
          float4 v = *px;
          v.x += acc[0]; v.y += acc[1]; v.z += acc[2]; v.w += acc[3];
          *px = v;
        }
      }
    }
    __syncthreads();

    // LN2: x -> S
    {
      int t = tid >> 2, q = tid & 3;
      float vals[16];
      float s = 0.f, s2 = 0.f;
#pragma unroll
      for (int i = 0; i < 4; i++) {
        float4 v = *(const float4*)&xf[t * 68 + q * 16 + i * 4];
        vals[i*4+0] = v.x; vals[i*4+1] = v.y; vals[i*4+2] = v.z; vals[i*4+3] = v.w;
        s += v.x + v.y + v.z + v.w;
        s2 += v.x*v.x + v.y*v.y + v.z*v.z + v.w*v.w;
      }
      s  += __shfl_xor(s, 1);  s  += __shfl_xor(s, 2);
      s2 += __shfl_xor(s2, 1); s2 += __shfl_xor(s2, 2);
      float mu = s * (1.f/64.f);
      float var = s2 * (1.f/64.f) - mu * mu;
      float inv = rsqrtf(fmaxf(var, 0.f) + 1e-5f);
      float tmp[16];
#pragma unroll
      for (int i = 0; i < 16; i++) {
        int c = q * 16 + i;
        tmp[i] = (vals[i] - mu) * inv * ln2_g[ly*64 + c] + ln2_b[ly*64 + c];
      }
      *(bf16x8*)&S[t * 72 + q * 16]     = pack8(tmp);
      *(bf16x8*)&S[t * 72 + q * 16 + 8] = pack8(tmp + 8);
    }
    __syncthreads();

    // ff1: F[t][o] = relu(S @ W1^T + b1), o<128
    {
      bf16x8 bs[2][2];
#pragma unroll
      for (int nt = 0; nt < 2; nt++)
#pragma unroll
        for (int kt = 0; kt < 2; kt++)
          bs[nt][kt] = *(const bf16x8*)&S[(nt * 16 + lr) * 72 + kt * 32 + hi * 8];
      const unsigned short* W1 = f1w_b + ly * 128 * 64;
      const float* B1 = f1b + ly * 128;
#pragma unroll
      for (int mi = 0; mi < 4; mi++) {
        int mt = w + mi * 2;
        bf16x8 a[2];
#pragma unroll
        for (int kt = 0; kt < 2; kt++)
          a[kt] = *(const bf16x8*)(W1 + (mt * 16 + lr) * 64 + kt * 32 + hi * 8);
        float4 b4 = *(const float4*)(B1 + mt * 16 + hi * 4);
#pragma unroll
        for (int nt = 0; nt < 2; nt++) {
          f32x4 acc; acc[0] = b4.x; acc[1] = b4.y; acc[2] = b4.z; acc[3] = b4.w;
#pragma unroll
          for (int kt = 0; kt < 2; kt++) acc = mfma16(a[kt], bs[nt][kt], acc);
#pragma unroll
          for (int r = 0; r < 4; r++) acc[r] = fmaxf(acc[r], 0.f);
          *(bf16x4*)&Fb[(nt * 16 + lr) * 136 + mt * 16 + hi * 4] = pack4(acc);
        }
      }
    }
    __syncthreads();

    // ff2: x += F @ W2^T + b2  (K=128 -> 4 ktiles)
    {
      bf16x8 bfr[2][4];
#pragma unroll
      for (int nt = 0; nt < 2; nt++)
#pragma unroll
        for (int kt = 0; kt < 4; kt++)
          bfr[nt][kt] = *(const bf16x8*)&Fb[(nt * 16 + lr) * 136 + kt * 32 + hi * 8];
      const unsigned short* W2 = f2w_b + ly * 64 * 128;
      const float* B2 = f2b + ly * 64;
#pragma unroll
      for (int mi = 0; mi < 2; mi++) {
        int mt = w + mi * 2;
        bf16x8 a[4];
#pragma unroll
        for (int kt = 0; kt < 4; kt++)
          a[kt] = *(const bf16x8*)(W2 + (mt * 16 + lr) * 128 + kt * 32 + hi * 8);
        float4 b4 = *(const float4*)(B2 + mt * 16 + hi * 4);
#pragma unroll
        for (int nt = 0; nt < 2; nt++) {
          f32x4 acc; acc[0] = b4.x; acc[1] = b4.y; acc[2] = b4.z; acc[3] = b4.w;
#pragma unroll
          for (int kt = 0; kt < 4; kt++) acc = mfma16(a[kt], bfr[nt][kt], acc);
          float4* px = (float4*)&xf[(nt * 16 + lr) * 68 + mt * 16 + hi * 4];
          float4 v = *px;
          v.x += acc[0]; v.y += acc[1]; v.z += acc[2]; v.w += acc[3];
          *px = v;
        }
      }
    }
  }
  __syncthreads();

  // ---- max pool over tokens (split rows across waves) ----
  {
    int c = tid & 63, rh = tid >> 6;
    float mx = -3.4e38f;
#pragma unroll
    for (int i = 0; i < 16; i++) mx = fmaxf(mx, xf[(rh * 16 + i) * 68 + c]);
    part[rh * 64 + c] = mx;
  }
  __syncthreads();

  // ---- output projection: 128 outputs, one per thread (f32) ----
  {
    int o = tid;
    const float* wr = out_w + o * 64;
    float a0 = 0.f, a1 = 0.f, a2 = 0.f, a3 = 0.f;
#pragma unroll
    for (int i = 0; i < 16; i++) {
      float4 wv = *(const float4*)(wr + i * 4);
      float4 p0 = *(const float4*)&part[i * 4];
      float4 p1 = *(const float4*)&part[64 + i * 4];
      a0 = fmaf(fmaxf(p0.x, p1.x), wv.x, a0);
      a1 = fmaf(fmaxf(p0.y, p1.y), wv.y, a1);
      a2 = fmaf(fmaxf(p0.z, p1.z), wv.z, a2);
      a3 = fmaf(fmaxf(p0.w, p1.w), wv.w, a3);
    }
    out[(size_t)m * OUTD + o] = out_b[o] + (a0 + a1) + (a2 + a3);
  }
}

extern "C" void kernel_launch(void* const* d_in, const int* in_sizes, int n_in,
                              void* d_out, int out_size, void* d_ws, size_t ws_size,
                              hipStream_t stream) {
  const float* xyz         = (const float*)d_in[0];
  const float* new_xyz     = (const float*)d_in[1];
  const float* features    = (const float*)d_in[2];
  const int*   group_idx   = (const int*)d_in[3];
  const unsigned char* empty_mask = (const unsigned char*)d_in[4];
  const float* pos_w1      = (const float*)d_in[5];
  const float* pos_bn_g    = (const float*)d_in[6];
  const float* pos_bn_b    = (const float*)d_in[7];
  const float* pos_bn_mean = (const float*)d_in[8];
  const float* pos_bn_var  = (const float*)d_in[9];
  const float* pos_w2      = (const float*)d_in[10];
  const float* pos_b2      = (const float*)d_in[11];
  const float* ln1_g       = (const float*)d_in[12];
  const float* ln1_b       = (const float*)d_in[13];
  const float* qkv_w       = (const float*)d_in[14];
  const float* qkv_b       = (const float*)d_in[15];
  const float* aow         = (const float*)d_in[16];
  const float* aob         = (const float*)d_in[17];
  const float* ln2_g       = (const float*)d_in[18];
  const float* ln2_b       = (const float*)d_in[19];
  const float* f1w         = (const float*)d_in[20];
  const float* f1b         = (const float*)d_in[21];
  const float* f2w         = (const float*)d_in[22];
  const float* f2b         = (const float*)d_in[23];
  const float* out_w       = (const float*)d_in[24];
  const float* out_b       = (const float*)d_in[25];
  float* out = (float*)d_out;
  unsigned char* ws = (unsigned char*)d_ws;

  hipLaunchKernelGGL(convert_weights, dim3(265), dim3(256), 0, stream,
                     qkv_w, aow, f1w, f2w, pos_w2, pos_w1,
                     pos_bn_g, pos_bn_b, pos_bn_mean, pos_bn_var, ws);

  hipLaunchKernelGGL(nvt_mfma, dim3(MQ), dim3(128), 0, stream,
                     xyz, new_xyz, features, group_idx, empty_mask,
                     pos_b2, ln1_g, ln1_b, qkv_b, aob, ln2_g, ln2_b,
                     f1b, f2b, out_w, out_b, ws, out);
}